// Round 6
// baseline (466.817 us; speedup 1.0000x reference)
//
#include <hip/hip_runtime.h>
#include <cstdint>
#include <cstddef>

#define DEV __device__ __forceinline__

typedef __attribute__((ext_vector_type(4))) float f32x4;
typedef __attribute__((ext_vector_type(8))) short bf16x8;
typedef unsigned short ushort_t;
typedef __attribute__((ext_vector_type(8))) unsigned short ushort8;

static constexpr int B_ = 16384, D_ = 1024, O_ = 2048;
static constexpr float LAM_ = 0.1f;

// ---------------- workspace layout (bytes) ----------------
static constexpr size_t WS_XBF   = 0;                               // B*D bf16
static constexpr size_t WS_XCBF  = WS_XBF   + (size_t)B_ * D_ * 2;  // B*D bf16
static constexpr size_t WS_HBF   = WS_XCBF  + (size_t)B_ * D_ * 2;  // B*D bf16
static constexpr size_t WS_CLSBF = WS_HBF   + (size_t)B_ * D_ * 2;  // O*D bf16
static constexpr size_t WS_CTWBF = WS_CLSBF + (size_t)O_ * D_ * 2;
static constexpr size_t WS_W2BF  = WS_CTWBF + (size_t)O_ * D_ * 2;
static constexpr size_t WS_W1BF  = WS_W2BF  + (size_t)O_ * D_ * 2;  // D*D bf16
static constexpr size_t WS_SMALL = WS_W1BF  + (size_t)D_ * D_ * 2;
// small block (byte offsets within WS_SMALL):
static constexpr size_t SM_COUNTS = 0;       // O f32   (zeroed)
static constexpr size_t SM_TSUM   = 8192;    // O f32   (zeroed)
static constexpr size_t SM_MSE    = 16384;   // B f32   (zeroed)
static constexpr size_t SM_ZERO_BYTES = 82176;
static constexpr size_t SM_S      = 82176;   // O f32   (fully overwritten)
static constexpr size_t SM_GWORD  = 90368;   // B f32   (fully overwritten)
static constexpr size_t SM_CEROW  = 155904;  // B f32   (fully overwritten)

// ---------------- helpers ----------------
DEV float wave_sum(float v) {
  #pragma unroll
  for (int o = 32; o; o >>= 1) v += __shfl_xor(v, o, 64);
  return v;
}

DEV ushort_t f2bf1(float f) {  // RNE float -> bf16 bits (finite inputs)
  union { float f; unsigned u; } c{f};
  unsigned r = c.u + 0x7fffu + ((c.u >> 16) & 1u);
  return (ushort_t)(r >> 16);
}

DEV float sigmoidf(float z) { return 1.0f / (1.0f + expf(-z)); }

DEV void gload_lds16(const ushort_t* g, ushort_t* l) {
  __builtin_amdgcn_global_load_lds((const __attribute__((address_space(1))) void*)g,
                                   (__attribute__((address_space(3))) void*)l, 16, 0, 0);
}

// stage one 256x32 bf16 K-half slot (16 KB) with 512 threads (2 x 16B chunks each).
// T2 swizzle (both-sides): LDS dest linear; SOURCE quarter pre-swizzled
// (q_src = (tid&3) ^ ((tid>>3)&3)); ds_read applies the same involution.
DEV void stage2(const ushort_t* __restrict__ s0, ushort_t* slot, int tid) {
  gload_lds16(s0, slot + tid * 8);
  gload_lds16(s0 + 128 * 1024, slot + (tid + 512) * 8);
}

DEV f32x4 mfma16(bf16x8 a, bf16x8 b, f32x4 c) {
  return __builtin_amdgcn_mfma_f32_16x16x32_bf16(a, b, c, 0, 0, 0);
}

// inline-asm ds_read_b128: invisible to the compiler's waitcnt pass, so no
// conservative vmcnt drain gets inserted against in-flight global_load_lds DMA.
// Consumption is guarded by explicit lgkmcnt(0) + sched_barrier(0) (rule #18).
#define DSR(dst, addr, off) \
  asm volatile("ds_read_b128 %0, %1 offset:" off : "=v"(dst) : "v"(addr))

// ---------------- K1: f32 -> bf16 convert (8 elems/thread) ----------------
__global__ __launch_bounds__(256) void f2bf_kernel(const float* __restrict__ in,
                                                   ushort_t* __restrict__ out, int n8) {
  int i = blockIdx.x * 256 + threadIdx.x;
  if (i >= n8) return;
  const float4* p = (const float4*)(in + (size_t)i * 8);
  float4 a = p[0], b = p[1];
  ushort8 o;
  o[0] = f2bf1(a.x); o[1] = f2bf1(a.y); o[2] = f2bf1(a.z); o[3] = f2bf1(a.w);
  o[4] = f2bf1(b.x); o[5] = f2bf1(b.y); o[6] = f2bf1(b.z); o[7] = f2bf1(b.w);
  *(ushort8*)(out + (size_t)i * 8) = o;
}

// ---------------- K2: per-row dots: t_i = x_i . cls[label_i]; g_word ----------------
__global__ __launch_bounds__(256) void rowdot_kernel(const float* __restrict__ x,
    const float* __restrict__ cls, const float* __restrict__ wg,
    const float* __restrict__ wgb, const int* __restrict__ labels,
    float* __restrict__ tsum, float* __restrict__ counts, float* __restrict__ g_word) {
  int wave = threadIdx.x >> 6, lane = threadIdx.x & 63;
  int row = blockIdx.x * 4 + wave;
  const float* xr = x + (size_t)row * D_;
  int lab = labels[row];
  const float* cr = cls + (size_t)max(lab, 0) * D_;
  float t = 0.f, g = 0.f;
  #pragma unroll
  for (int j = 0; j < 4; ++j) {
    int d = j * 256 + lane * 4;
    float4 xv = *(const float4*)(xr + d);
    float4 cv = *(const float4*)(cr + d);
    float4 wv = *(const float4*)(wg + d);
    t += xv.x * cv.x + xv.y * cv.y + xv.z * cv.z + xv.w * cv.w;
    g += xv.x * wv.x + xv.y * wv.y + xv.z * wv.z + xv.w * wv.w;
  }
  t = wave_sum(t); g = wave_sum(g);
  if (lane == 0) {
    if (lab >= 0) {
      atomicAdd(&tsum[lab], t);
      atomicAdd(&counts[lab], 1.0f);
    }
    g_word[row] = sigmoidf(g + wgb[0]);
  }
}

// ---------------- K3: s[o] = dot(r_sub[o], classifier[o]) ----------------
__global__ __launch_bounds__(256) void scls_kernel(const float* __restrict__ cls,
    const float* __restrict__ none_t, const float* __restrict__ hist,
    const int* __restrict__ hcnt, const float* __restrict__ counts,
    const float* __restrict__ tsum, float* __restrict__ s) {
  int wave = threadIdx.x >> 6, lane = threadIdx.x & 63;
  int o = blockIdx.x * 4 + wave;
  if (o >= O_) return;
  const float* cr = cls + (size_t)o * D_;
  const float* src = (o == 0) ? none_t : hist + (size_t)(o - 1) * D_;
  float dv = 0.f;
  #pragma unroll
  for (int j = 0; j < 4; ++j) {
    int d = j * 256 + lane * 4;
    float4 a = *(const float4*)(src + d);
    float4 c = *(const float4*)(cr + d);
    dv += a.x * c.x + a.y * c.y + a.z * c.z + a.w * c.w;
  }
  dv = wave_sum(dv);
  if (lane == 0) {
    if (o == 0) { s[0] = dv; }
    else {
      float co = counts[o];
      bool has = co > 0.f;
      int cnt = hcnt[o - 1] + (has ? 1 : 0);
      float denom = 1.f - powf(0.9f, (float)max(cnt, 1));
      float val = has ? (0.9f * dv + tsum[o] / fmaxf(co, 1.f)) : dv;
      s[o] = (0.1f / denom) * val;
    }
  }
}

// ---------------- 8-phase 256x256 GEMM (BK=64, 8 waves, 128KB LDS ring) ----------------
// LDS bytes: A slots at (k&3)*16384, B slots at 65536 + (k&3)*16384.
// Per tile t (ksubs 2t,2t+1): 4 phases, stages q0:A(2t+3) q1:B(2t+3) q2:A(2t+4) q3:B(2t+4).
// Counted vmcnt(8) at p1/p3; ds_reads are inline asm (see DSR).
template<bool S01, bool S23, int W1, int W3>
DEV void tile8(int t, const ushort_t* __restrict__ sA0, const ushort_t* __restrict__ sB0,
               ushort_t* lds, int tid, unsigned aoffB, unsigned boffB, f32x4 (&acc)[8][4]) {
  const unsigned s0 = (unsigned)(((2 * t) & 3) * 16384);
  const unsigned s1 = (unsigned)(((2 * t + 1) & 3) * 16384);
  unsigned aA0 = aoffB + s0, aB0 = boffB + 65536u + s0;
  unsigned aA1 = aoffB + s1, aB1 = boffB + 65536u + s1;
  bf16x8 afr[4], bfr[4];
  // ---- phase 0: read B(k0) + A(k0) m0-3 ; stage A(2t+3)
  DSR(bfr[0], aB0, "0"); DSR(bfr[1], aB0, "1024"); DSR(bfr[2], aB0, "2048"); DSR(bfr[3], aB0, "3072");
  DSR(afr[0], aA0, "0"); DSR(afr[1], aA0, "1024"); DSR(afr[2], aA0, "2048"); DSR(afr[3], aA0, "3072");
  if constexpr (S01) stage2(sA0 + (size_t)(2 * t + 3) * 32, lds + ((2 * t + 3) & 3) * 8192, tid);
  __builtin_amdgcn_s_barrier();
  asm volatile("s_waitcnt lgkmcnt(0)");
  __builtin_amdgcn_sched_barrier(0);
  __builtin_amdgcn_s_setprio(1);
  #pragma unroll
  for (int m = 0; m < 4; m++)
    #pragma unroll
    for (int n = 0; n < 4; n++) acc[m][n] = mfma16(afr[m], bfr[n], acc[m][n]);
  __builtin_amdgcn_s_setprio(0);
  __builtin_amdgcn_s_barrier();
  // ---- phase 1: read A(k0) m4-7 ; stage B(2t+3) ; W1
  DSR(afr[0], aA0, "4096"); DSR(afr[1], aA0, "5120"); DSR(afr[2], aA0, "6144"); DSR(afr[3], aA0, "7168");
  if constexpr (S01) stage2(sB0 + (size_t)(2 * t + 3) * 32, lds + 32768 + ((2 * t + 3) & 3) * 8192, tid);
  __builtin_amdgcn_s_barrier();
  asm volatile("s_waitcnt lgkmcnt(0)");
  __builtin_amdgcn_sched_barrier(0);
  __builtin_amdgcn_s_setprio(1);
  #pragma unroll
  for (int m = 0; m < 4; m++)
    #pragma unroll
    for (int n = 0; n < 4; n++) acc[m + 4][n] = mfma16(afr[m], bfr[n], acc[m + 4][n]);
  __builtin_amdgcn_s_setprio(0);
  if constexpr (W1 == 8) asm volatile("s_waitcnt vmcnt(8)" ::: "memory");
  else if constexpr (W1 == 4) asm volatile("s_waitcnt vmcnt(4)" ::: "memory");
  else if constexpr (W1 == 0) asm volatile("s_waitcnt vmcnt(0)" ::: "memory");
  __builtin_amdgcn_s_barrier();
  // ---- phase 2: read B(k1) + A(k1) m0-3 ; stage A(2t+4)
  DSR(bfr[0], aB1, "0"); DSR(bfr[1], aB1, "1024"); DSR(bfr[2], aB1, "2048"); DSR(bfr[3], aB1, "3072");
  DSR(afr[0], aA1, "0"); DSR(afr[1], aA1, "1024"); DSR(afr[2], aA1, "2048"); DSR(afr[3], aA1, "3072");
  if constexpr (S23) stage2(sA0 + (size_t)(2 * t + 4) * 32, lds + ((2 * t + 4) & 3) * 8192, tid);
  __builtin_amdgcn_s_barrier();
  asm volatile("s_waitcnt lgkmcnt(0)");
  __builtin_amdgcn_sched_barrier(0);
  __builtin_amdgcn_s_setprio(1);
  #pragma unroll
  for (int m = 0; m < 4; m++)
    #pragma unroll
    for (int n = 0; n < 4; n++) acc[m][n] = mfma16(afr[m], bfr[n], acc[m][n]);
  __builtin_amdgcn_s_setprio(0);
  __builtin_amdgcn_s_barrier();
  // ---- phase 3: read A(k1) m4-7 ; stage B(2t+4) ; W3
  DSR(afr[0], aA1, "4096"); DSR(afr[1], aA1, "5120"); DSR(afr[2], aA1, "6144"); DSR(afr[3], aA1, "7168");
  if constexpr (S23) stage2(sB0 + (size_t)(2 * t + 4) * 32, lds + 32768 + ((2 * t + 4) & 3) * 8192, tid);
  __builtin_amdgcn_s_barrier();
  asm volatile("s_waitcnt lgkmcnt(0)");
  __builtin_amdgcn_sched_barrier(0);
  __builtin_amdgcn_s_setprio(1);
  #pragma unroll
  for (int m = 0; m < 4; m++)
    #pragma unroll
    for (int n = 0; n < 4; n++) acc[m + 4][n] = mfma16(afr[m], bfr[n], acc[m + 4][n]);
  __builtin_amdgcn_s_setprio(0);
  if constexpr (W3 == 8) asm volatile("s_waitcnt vmcnt(8)" ::: "memory");
  else if constexpr (W3 == 4) asm volatile("s_waitcnt vmcnt(4)" ::: "memory");
  else if constexpr (W3 == 2) asm volatile("s_waitcnt vmcnt(2)" ::: "memory");
  else if constexpr (W3 == 0) asm volatile("s_waitcnt vmcnt(0)" ::: "memory");
  __builtin_amdgcn_s_barrier();
}

// EPI: 0 = h (bias+gelu -> bf16 hout, N=1024); 1 = ctx (bias -> f32 fout)
//      2 = att (bias; read ctx from fout; mse partials only)
//      3 = xc  (read ctx from fout; w = gw*sigmoid(ctx); fout = (1-w)*xc + w*s)
template<int EPI, int NTSHIFT>
__global__ __launch_bounds__(512, 2) void gemm8_kernel(
    const ushort_t* __restrict__ A, const ushort_t* __restrict__ Bmat,
    const float* __restrict__ bias, float* __restrict__ fout,
    ushort_t* __restrict__ hout, const float* __restrict__ g_word,
    const float* __restrict__ svec, float* __restrict__ mse_row) {
  __shared__ __align__(16) ushort_t lds[65536];  // 128 KB
  const int tid = threadIdx.x, lane = tid & 63, wave = tid >> 6;
  const int wr = wave >> 2, wc = wave & 3;  // 2 x 4 wave grid
  const int nwg = 64 << NTSHIFT, cpx = nwg >> 3;
  int bid = blockIdx.x;
  int wg = (bid & 7) * cpx + (bid >> 3);     // XCD swizzle (nwg % 8 == 0)
  const int bm = wg >> NTSHIFT, bn = wg & ((1 << NTSHIFT) - 1);
  const int NCOL = 256 << NTSHIFT;           // output row stride
  // staging source base; T2: source quarter pre-swizzled by ((row>>1)&3)
  const int qsrc = (tid & 3) ^ ((tid >> 3) & 3);
  const ushort_t* sA0 = A + ((size_t)bm * 256 + (tid >> 2)) * 1024 + qsrc * 8;
  const ushort_t* sB0 = Bmat + ((size_t)bn * 256 + (tid >> 2)) * 1024 + qsrc * 8;
  // ds_read quarter: same involution, per-lane constant (indep of m/n); BYTE offsets
  const int qrd = (lane >> 4) ^ (((lane & 15) >> 1) & 3);
  const unsigned aoffB = (unsigned)(((wr * 128 + (lane & 15)) * 32 + qrd * 8) * 2);
  const unsigned boffB = (unsigned)(((wc * 64 + (lane & 15)) * 32 + qrd * 8) * 2);
  f32x4 acc[8][4] = {};
  // prologue: stage ksubs 0,1,2 (12 loads); vmcnt(8) confirms slots 0,1.
  stage2(sA0, lds, tid);
  stage2(sB0, lds + 32768, tid);
  stage2(sA0 + 32, lds + 8192, tid);
  stage2(sB0 + 32, lds + 32768 + 8192, tid);
  stage2(sA0 + 64, lds + 2 * 8192, tid);
  stage2(sB0 + 64, lds + 32768 + 2 * 8192, tid);
  asm volatile("s_waitcnt vmcnt(8)" ::: "memory");
  __builtin_amdgcn_s_barrier();
  for (int t = 0; t < 14; ++t)
    tile8<true, true, 8, 8>(t, sA0, sB0, lds, tid, aoffB, boffB, acc);
  tile8<true, false, 8, 4>(14, sA0, sB0, lds, tid, aoffB, boffB, acc);
  tile8<false, false, 0, 0>(15, sA0, sB0, lds, tid, aoffB, boffB, acc);
  // ---- epilogue ----
  #pragma unroll
  for (int m = 0; m < 8; m++) {
    #pragma unroll
    for (int i = 0; i < 4; i++) {
      int row = bm * 256 + wr * 128 + m * 16 + (lane >> 4) * 4 + i;
      float gw = 0.f, msum = 0.f;
      if constexpr (EPI == 3) gw = g_word[row];
      #pragma unroll
      for (int n = 0; n < 4; n++) {
        int col = bn * 256 + wc * 64 + n * 16 + (lane & 15);
        float v = acc[m][n][i];
        if constexpr (EPI == 0) {
          float z = v + bias[col];
          float gl = 0.5f * z * (1.f + erff(z * 0.70710678118f));
          hout[(size_t)row * 1024 + col] = f2bf1(gl);
        } else if constexpr (EPI == 1) {
          fout[(size_t)row * NCOL + col] = v + bias[col];
        } else if constexpr (EPI == 2) {
          float att = v + bias[col];
          float ctx = fout[(size_t)row * NCOL + col];
          float d = ctx - att;
          msum += d * d;
        } else {
          size_t off = (size_t)row * NCOL + col;
          float ctx = fout[off];
          float w = gw * sigmoidf(ctx);
          fout[off] = (1.f - w) * v + w * svec[col];
        }
      }
      if constexpr (EPI == 2) {
        #pragma unroll
        for (int o = 1; o < 16; o <<= 1) msum += __shfl_xor(msum, o, 64);
        if ((lane & 15) == 0) atomicAdd(&mse_row[row], msum);
      }
    }
  }
}

// ---------------- K7: per-row log-softmax CE ----------------
__global__ __launch_bounds__(256) void ce_kernel(const float* __restrict__ logits,
    const int* __restrict__ labels, float* __restrict__ ce_row) {
  int row = blockIdx.x, t = threadIdx.x, lane = t & 63, wave = t >> 6;
  const float* lr = logits + (size_t)row * O_;
  float v[8];
  float m = -INFINITY;
  #pragma unroll
  for (int j = 0; j < 8; j++) { v[j] = lr[t + j * 256]; m = fmaxf(m, v[j]); }
  #pragma unroll
  for (int o = 32; o; o >>= 1) m = fmaxf(m, __shfl_xor(m, o, 64));
  __shared__ float red[8];
  if (lane == 0) red[wave] = m;
  __syncthreads();
  m = fmaxf(fmaxf(red[0], red[1]), fmaxf(red[2], red[3]));
  float se = 0.f;
  #pragma unroll
  for (int j = 0; j < 8; j++) se += expf(v[j] - m);
  se = wave_sum(se);
  if (lane == 0) red[4 + wave] = se;
  __syncthreads();
  if (t == 0) {
    float bs = red[4] + red[5] + red[6] + red[7];
    int lab = labels[row];
    float nll = 0.f;
    if (lab >= 0) nll = -(lr[lab] - m - logf(bs));
    ce_row[row] = nll;
  }
}

// ---------------- K8: final scalar ----------------
__global__ __launch_bounds__(256) void finalize_kernel(const float* __restrict__ ce_row,
    const float* __restrict__ mse_row, const int* __restrict__ labels,
    float* __restrict__ out0) {
  int t = threadIdx.x, lane = t & 63, wave = t >> 6;
  float sn = 0.f, sm = 0.f, sc = 0.f;
  for (int i = t; i < B_; i += 256) {
    if (labels[i] >= 0) { sn += ce_row[i]; sm += mse_row[i]; sc += 1.f; }
  }
  sn = wave_sum(sn); sm = wave_sum(sm); sc = wave_sum(sc);
  __shared__ float r0[4], r1[4], r2[4];
  if (lane == 0) { r0[wave] = sn; r1[wave] = sm; r2[wave] = sc; }
  __syncthreads();
  if (t == 0) {
    float a = r0[0] + r0[1] + r0[2] + r0[3];
    float b = r1[0] + r1[1] + r1[2] + r1[3];
    float c = r2[0] + r2[1] + r2[2] + r2[3];
    out0[0] = (a + LAM_ * (b / (float)O_)) / fmaxf(c, 1.f);
  }
}

// ---------------- launch ----------------
extern "C" void kernel_launch(void* const* d_in, const int* in_sizes, int n_in,
                              void* d_out, int out_size, void* d_ws, size_t ws_size,
                              hipStream_t stream) {
  const float* x        = (const float*)d_in[0];
  const float* x_ctx    = (const float*)d_in[1];
  const float* cls      = (const float*)d_in[2];
  const float* none_t   = (const float*)d_in[3];
  const float* ctx_q_w  = (const float*)d_in[4];
  const float* ctx_q_b  = (const float*)d_in[5];
  const float* word_g_w = (const float*)d_in[6];
  const float* word_g_b = (const float*)d_in[7];
  const float* w1       = (const float*)d_in[8];
  const float* b1       = (const float*)d_in[9];
  const float* w2       = (const float*)d_in[10];
  const float* b2       = (const float*)d_in[11];
  const float* hist     = (const float*)d_in[12];
  const int*   hcnt     = (const int*)d_in[13];
  const int*   labels   = (const int*)d_in[14];

  float* out  = (float*)d_out;
  float* out1 = out + 1;  // logits [B x O]
  char* ws = (char*)d_ws;

  ushort_t* xbf   = (ushort_t*)(ws + WS_XBF);
  ushort_t* xcbf  = (ushort_t*)(ws + WS_XCBF);
  ushort_t* hbf   = (ushort_t*)(ws + WS_HBF);
  ushort_t* clsbf = (ushort_t*)(ws + WS_CLSBF);
  ushort_t* ctwbf = (ushort_t*)(ws + WS_CTWBF);
  ushort_t* w2bf  = (ushort_t*)(ws + WS_W2BF);
  ushort_t* w1bf  = (ushort_t*)(ws + WS_W1BF);
  float* counts   = (float*)(ws + WS_SMALL + SM_COUNTS);
  float* tsum     = (float*)(ws + WS_SMALL + SM_TSUM);
  float* mse_row  = (float*)(ws + WS_SMALL + SM_MSE);
  float* s        = (float*)(ws + WS_SMALL + SM_S);
  float* g_word   = (float*)(ws + WS_SMALL + SM_GWORD);
  float* ce_row   = (float*)(ws + WS_SMALL + SM_CEROW);

  hipMemsetAsync(ws + WS_SMALL, 0, SM_ZERO_BYTES, stream);

  f2bf_kernel<<<8192, 256, 0, stream>>>(x, xbf, B_ * D_ / 8);
  f2bf_kernel<<<8192, 256, 0, stream>>>(x_ctx, xcbf, B_ * D_ / 8);
  f2bf_kernel<<<1024, 256, 0, stream>>>(cls, clsbf, O_ * D_ / 8);
  f2bf_kernel<<<1024, 256, 0, stream>>>(ctx_q_w, ctwbf, O_ * D_ / 8);
  f2bf_kernel<<<1024, 256, 0, stream>>>(w2, w2bf, O_ * D_ / 8);
  f2bf_kernel<<<512, 256, 0, stream>>>(w1, w1bf, D_ * D_ / 8);

  rowdot_kernel<<<B_ / 4, 256, 0, stream>>>(x, cls, word_g_w, word_g_b, labels,
                                            tsum, counts, g_word);
  scls_kernel<<<O_ / 4, 256, 0, stream>>>(cls, none_t, hist, hcnt, counts, tsum, s);

  // h = gelu(x @ w1^T + b1)          [16384 x 1024] bf16
  gemm8_kernel<0, 2><<<64 * 4, 512, 0, stream>>>(xbf, w1bf, b1, nullptr, hbf,
                                                 nullptr, nullptr, nullptr);
  // ctx = x_ctx @ ctx_q_w^T + ctx_b  -> out1 (f32)
  gemm8_kernel<1, 3><<<64 * 8, 512, 0, stream>>>(xcbf, ctwbf, ctx_q_b, out1, nullptr,
                                                 nullptr, nullptr, nullptr);
  // att = h @ w2^T + b2 ; mse partials vs ctx (read out1)
  gemm8_kernel<2, 3><<<64 * 8, 512, 0, stream>>>(hbf, w2bf, b2, out1, nullptr,
                                                 nullptr, nullptr, mse_row);
  // xc = x @ cls^T ; w = gw*sigmoid(ctx) ; out1 = (1-w)*xc + w*s
  gemm8_kernel<3, 3><<<64 * 8, 512, 0, stream>>>(xbf, clsbf, nullptr, out1, nullptr,
                                                 g_word, s, nullptr);

  ce_kernel<<<B_, 256, 0, stream>>>(out1, labels, ce_row);
  finalize_kernel<<<1, 256, 0, stream>>>(ce_row, mse_row, labels, out);
}

// Round 7
// 455.013 us; speedup vs baseline: 1.0259x; 1.0259x over previous
//
#include <hip/hip_runtime.h>
#include <cstdint>
#include <cstddef>

#define DEV __device__ __forceinline__

typedef __attribute__((ext_vector_type(4))) float f32x4;
typedef __attribute__((ext_vector_type(8))) short bf16x8;
typedef unsigned short ushort_t;
typedef __attribute__((ext_vector_type(8))) unsigned short ushort8;

static constexpr int B_ = 16384, D_ = 1024, O_ = 2048;
static constexpr float LAM_ = 0.1f;

// ---------------- workspace layout (bytes) ----------------
static constexpr size_t WS_XBF   = 0;                               // B*D bf16
static constexpr size_t WS_XCBF  = WS_XBF   + (size_t)B_ * D_ * 2;  // B*D bf16
static constexpr size_t WS_HBF   = WS_XCBF  + (size_t)B_ * D_ * 2;  // B*D bf16
static constexpr size_t WS_CLSBF = WS_HBF   + (size_t)B_ * D_ * 2;  // O*D bf16
static constexpr size_t WS_CTWBF = WS_CLSBF + (size_t)O_ * D_ * 2;
static constexpr size_t WS_W2BF  = WS_CTWBF + (size_t)O_ * D_ * 2;
static constexpr size_t WS_W1BF  = WS_W2BF  + (size_t)O_ * D_ * 2;  // D*D bf16
static constexpr size_t WS_SMALL = WS_W1BF  + (size_t)D_ * D_ * 2;
// small block (byte offsets within WS_SMALL):
static constexpr size_t SM_COUNTS = 0;       // O f32   (zeroed)
static constexpr size_t SM_TSUM   = 8192;    // O f32   (zeroed)
static constexpr size_t SM_MSE    = 16384;   // B f32   (zeroed)
static constexpr size_t SM_ZERO_BYTES = 82176;
static constexpr size_t SM_S      = 82176;   // O f32   (fully overwritten)
static constexpr size_t SM_GWORD  = 90368;   // B f32   (fully overwritten)
static constexpr size_t SM_CEROW  = 155904;  // B f32   (fully overwritten)

// ---------------- helpers ----------------
DEV float wave_sum(float v) {
  #pragma unroll
  for (int o = 32; o; o >>= 1) v += __shfl_xor(v, o, 64);
  return v;
}

DEV ushort_t f2bf1(float f) {  // RNE float -> bf16 bits (finite inputs)
  union { float f; unsigned u; } c{f};
  unsigned r = c.u + 0x7fffu + ((c.u >> 16) & 1u);
  return (ushort_t)(r >> 16);
}

DEV float sigmoidf(float z) { return 1.0f / (1.0f + expf(-z)); }

DEV void gload_lds16(const ushort_t* g, ushort_t* l) {
  __builtin_amdgcn_global_load_lds((const __attribute__((address_space(1))) void*)g,
                                   (__attribute__((address_space(3))) void*)l, 16, 0, 0);
}

// stage one 256x32 bf16 K-half slot (16 KB) with 512 threads (2 x 16B chunks each).
// T2 swizzle (both-sides): LDS dest linear; SOURCE quarter pre-swizzled
// (q_src = (tid&3) ^ ((tid>>3)&3)); ds_read applies the same involution.
DEV void stage2(const ushort_t* __restrict__ s0, ushort_t* slot, int tid) {
  gload_lds16(s0, slot + tid * 8);
  gload_lds16(s0 + 128 * 1024, slot + (tid + 512) * 8);
}

DEV f32x4 mfma16(bf16x8 a, bf16x8 b, f32x4 c) {
  return __builtin_amdgcn_mfma_f32_16x16x32_bf16(a, b, c, 0, 0, 0);
}

// inline-asm ds_read_b128 (asm volatile: mutually ordered; MFMA consumption is
// fenced by lgkmcnt + sched_barrier(0) per rule #18).
#define DSR(dst, addr, off) \
  asm volatile("ds_read_b128 %0, %1 offset:" off : "=v"(dst) : "v"(addr))

template<int N> DEV void wait_vm() {
  if constexpr (N == 8)      asm volatile("s_waitcnt vmcnt(8)" ::: "memory");
  else if constexpr (N == 6) asm volatile("s_waitcnt vmcnt(6)" ::: "memory");
  else if constexpr (N == 4) asm volatile("s_waitcnt vmcnt(4)" ::: "memory");
  else if constexpr (N == 2) asm volatile("s_waitcnt vmcnt(2)" ::: "memory");
  else                       asm volatile("s_waitcnt vmcnt(0)" ::: "memory");
}

// ---------------- K1: f32 -> bf16 convert (8 elems/thread) ----------------
__global__ __launch_bounds__(256) void f2bf_kernel(const float* __restrict__ in,
                                                   ushort_t* __restrict__ out, int n8) {
  int i = blockIdx.x * 256 + threadIdx.x;
  if (i >= n8) return;
  const float4* p = (const float4*)(in + (size_t)i * 8);
  float4 a = p[0], b = p[1];
  ushort8 o;
  o[0] = f2bf1(a.x); o[1] = f2bf1(a.y); o[2] = f2bf1(a.z); o[3] = f2bf1(a.w);
  o[4] = f2bf1(b.x); o[5] = f2bf1(b.y); o[6] = f2bf1(b.z); o[7] = f2bf1(b.w);
  *(ushort8*)(out + (size_t)i * 8) = o;
}

// ---------------- K2: per-row dots: t_i = x_i . cls[label_i]; g_word ----------------
__global__ __launch_bounds__(256) void rowdot_kernel(const float* __restrict__ x,
    const float* __restrict__ cls, const float* __restrict__ wg,
    const float* __restrict__ wgb, const int* __restrict__ labels,
    float* __restrict__ tsum, float* __restrict__ counts, float* __restrict__ g_word) {
  int wave = threadIdx.x >> 6, lane = threadIdx.x & 63;
  int row = blockIdx.x * 4 + wave;
  const float* xr = x + (size_t)row * D_;
  int lab = labels[row];
  const float* cr = cls + (size_t)max(lab, 0) * D_;
  float t = 0.f, g = 0.f;
  #pragma unroll
  for (int j = 0; j < 4; ++j) {
    int d = j * 256 + lane * 4;
    float4 xv = *(const float4*)(xr + d);
    float4 cv = *(const float4*)(cr + d);
    float4 wv = *(const float4*)(wg + d);
    t += xv.x * cv.x + xv.y * cv.y + xv.z * cv.z + xv.w * cv.w;
    g += xv.x * wv.x + xv.y * wv.y + xv.z * wv.z + xv.w * wv.w;
  }
  t = wave_sum(t); g = wave_sum(g);
  if (lane == 0) {
    if (lab >= 0) {
      atomicAdd(&tsum[lab], t);
      atomicAdd(&counts[lab], 1.0f);
    }
    g_word[row] = sigmoidf(g + wgb[0]);
  }
}

// ---------------- K3: s[o] = dot(r_sub[o], classifier[o]) ----------------
__global__ __launch_bounds__(256) void scls_kernel(const float* __restrict__ cls,
    const float* __restrict__ none_t, const float* __restrict__ hist,
    const int* __restrict__ hcnt, const float* __restrict__ counts,
    const float* __restrict__ tsum, float* __restrict__ s) {
  int wave = threadIdx.x >> 6, lane = threadIdx.x & 63;
  int o = blockIdx.x * 4 + wave;
  if (o >= O_) return;
  const float* cr = cls + (size_t)o * D_;
  const float* src = (o == 0) ? none_t : hist + (size_t)(o - 1) * D_;
  float dv = 0.f;
  #pragma unroll
  for (int j = 0; j < 4; ++j) {
    int d = j * 256 + lane * 4;
    float4 a = *(const float4*)(src + d);
    float4 c = *(const float4*)(cr + d);
    dv += a.x * c.x + a.y * c.y + a.z * c.z + a.w * c.w;
  }
  dv = wave_sum(dv);
  if (lane == 0) {
    if (o == 0) { s[0] = dv; }
    else {
      float co = counts[o];
      bool has = co > 0.f;
      int cnt = hcnt[o - 1] + (has ? 1 : 0);
      float denom = 1.f - powf(0.9f, (float)max(cnt, 1));
      float val = has ? (0.9f * dv + tsum[o] / fmaxf(co, 1.f)) : dv;
      s[o] = (0.1f / denom) * val;
    }
  }
}

// ---- 4-phase/K-tile 256x256 GEMM, register-double-buffered frags (r7) ----
// LDS bytes: A slots at (k&3)*16384, B slots at 65536 + (k&3)*16384.
// Phase p: {issue ds_reads for MFMA_{p+1} | stage | lgkmcnt(counted) | MFMA_p |
//           vmcnt(W) | s_barrier}.  Reads stream on the LDS port during MFMA.
// lgkm counts = reads just issued (4 or 8); vmcnt(6)/phase confirms the stage
// issued 4 phases prior (just-in-time for its hoisted read). Tail: t14 (6,6,4,2),
// t15 (0,0,0,0)+lgkm(0) — every stage confirmed before its read (ledger r7).
template<bool S01, bool S23, int W0, int W1, int W2, int W3, bool RLAST>
DEV void tile4(int t, const ushort_t* __restrict__ sA0, const ushort_t* __restrict__ sB0,
               ushort_t* lds, int tid, unsigned aoffB, unsigned boffB,
               bf16x8 (&bA)[2][4], bf16x8 (&bB)[2][4], f32x4 (&acc)[8][4]) {
  const unsigned sl0 = (unsigned)(((2 * t) & 3) * 16384);
  const unsigned sl1 = (unsigned)(((2 * t + 1) & 3) * 16384);
  const unsigned sl2 = (unsigned)(((2 * t + 2) & 3) * 16384);
  const unsigned aA0 = aoffB + sl0;
  const unsigned aA1 = aoffB + sl1, aB1 = boffB + 65536u + sl1;
  const unsigned aA2 = aoffB + sl2, aB2 = boffB + 65536u + sl2;
  // ---- p0: reads A(k0)hi -> bA[1]; stage A(2t+3); MFMA k0-lo = (bA[0], bB[0])
  DSR(bA[1][0], aA0, "4096"); DSR(bA[1][1], aA0, "5120");
  DSR(bA[1][2], aA0, "6144"); DSR(bA[1][3], aA0, "7168");
  if constexpr (S01) stage2(sA0 + (size_t)(2 * t + 3) * 32, lds + ((2 * t + 3) & 3) * 8192, tid);
  asm volatile("s_waitcnt lgkmcnt(4)");
  __builtin_amdgcn_sched_barrier(0);
  __builtin_amdgcn_s_setprio(1);
  #pragma unroll
  for (int m = 0; m < 4; m++)
    #pragma unroll
    for (int n = 0; n < 4; n++) acc[m][n] = mfma16(bA[0][m], bB[0][n], acc[m][n]);
  __builtin_amdgcn_s_setprio(0);
  __builtin_amdgcn_sched_barrier(0);
  wait_vm<W0>();
  __builtin_amdgcn_s_barrier();
  // ---- p1: reads B(k1)->bB[1], A(k1)lo->bA[0]; stage B(2t+3); MFMA k0-hi = (bA[1], bB[0])
  DSR(bB[1][0], aB1, "0"); DSR(bB[1][1], aB1, "1024");
  DSR(bB[1][2], aB1, "2048"); DSR(bB[1][3], aB1, "3072");
  DSR(bA[0][0], aA1, "0"); DSR(bA[0][1], aA1, "1024");
  DSR(bA[0][2], aA1, "2048"); DSR(bA[0][3], aA1, "3072");
  if constexpr (S01) stage2(sB0 + (size_t)(2 * t + 3) * 32, lds + 32768 + ((2 * t + 3) & 3) * 8192, tid);
  asm volatile("s_waitcnt lgkmcnt(8)");
  __builtin_amdgcn_sched_barrier(0);
  __builtin_amdgcn_s_setprio(1);
  #pragma unroll
  for (int m = 0; m < 4; m++)
    #pragma unroll
    for (int n = 0; n < 4; n++) acc[m + 4][n] = mfma16(bA[1][m], bB[0][n], acc[m + 4][n]);
  __builtin_amdgcn_s_setprio(0);
  __builtin_amdgcn_sched_barrier(0);
  wait_vm<W1>();
  __builtin_amdgcn_s_barrier();
  // ---- p2: reads A(k1)hi -> bA[1]; stage A(2t+4); MFMA k1-lo = (bA[0], bB[1])
  DSR(bA[1][0], aA1, "4096"); DSR(bA[1][1], aA1, "5120");
  DSR(bA[1][2], aA1, "6144"); DSR(bA[1][3], aA1, "7168");
  if constexpr (S23) stage2(sA0 + (size_t)(2 * t + 4) * 32, lds + ((2 * t + 4) & 3) * 8192, tid);
  asm volatile("s_waitcnt lgkmcnt(4)");
  __builtin_amdgcn_sched_barrier(0);
  __builtin_amdgcn_s_setprio(1);
  #pragma unroll
  for (int m = 0; m < 4; m++)
    #pragma unroll
    for (int n = 0; n < 4; n++) acc[m][n] = mfma16(bA[0][m], bB[1][n], acc[m][n]);
  __builtin_amdgcn_s_setprio(0);
  __builtin_amdgcn_sched_barrier(0);
  wait_vm<W2>();
  __builtin_amdgcn_s_barrier();
  // ---- p3: reads B(k0')->bB[0], A(k0')lo->bA[0]; stage B(2t+4); MFMA k1-hi = (bA[1], bB[1])
  if constexpr (!RLAST) {
    DSR(bB[0][0], aB2, "0"); DSR(bB[0][1], aB2, "1024");
    DSR(bB[0][2], aB2, "2048"); DSR(bB[0][3], aB2, "3072");
    DSR(bA[0][0], aA2, "0"); DSR(bA[0][1], aA2, "1024");
    DSR(bA[0][2], aA2, "2048"); DSR(bA[0][3], aA2, "3072");
  }
  if constexpr (S23) stage2(sB0 + (size_t)(2 * t + 4) * 32, lds + 32768 + ((2 * t + 4) & 3) * 8192, tid);
  if constexpr (RLAST) asm volatile("s_waitcnt lgkmcnt(0)");
  else                 asm volatile("s_waitcnt lgkmcnt(8)");
  __builtin_amdgcn_sched_barrier(0);
  __builtin_amdgcn_s_setprio(1);
  #pragma unroll
  for (int m = 0; m < 4; m++)
    #pragma unroll
    for (int n = 0; n < 4; n++) acc[m + 4][n] = mfma16(bA[1][m], bB[1][n], acc[m + 4][n]);
  __builtin_amdgcn_s_setprio(0);
  __builtin_amdgcn_sched_barrier(0);
  wait_vm<W3>();
  __builtin_amdgcn_s_barrier();
}

// EPI: 0 = h (bias+gelu -> bf16 hout, N=1024); 1 = ctx (bias -> f32 fout)
//      2 = att (bias; read ctx from fout; mse partials only)
//      3 = xc  (read ctx from fout; w = gw*sigmoid(ctx); fout = (1-w)*xc + w*s)
template<int EPI, int NTSHIFT>
__global__ __launch_bounds__(512, 2) void gemm8_kernel(
    const ushort_t* __restrict__ A, const ushort_t* __restrict__ Bmat,
    const float* __restrict__ bias, float* __restrict__ fout,
    ushort_t* __restrict__ hout, const float* __restrict__ g_word,
    const float* __restrict__ svec, float* __restrict__ mse_row) {
  __shared__ __align__(16) ushort_t lds[65536];  // 128 KB
  const int tid = threadIdx.x, lane = tid & 63, wave = tid >> 6;
  const int wr = wave >> 2, wc = wave & 3;  // 2 x 4 wave grid
  const int nwg = 64 << NTSHIFT, cpx = nwg >> 3;
  int bid = blockIdx.x;
  int wg = (bid & 7) * cpx + (bid >> 3);     // XCD swizzle (nwg % 8 == 0)
  const int bm = wg >> NTSHIFT, bn = wg & ((1 << NTSHIFT) - 1);
  const int NCOL = 256 << NTSHIFT;           // output row stride
  // staging source base; T2: source quarter pre-swizzled by ((row>>1)&3)
  const int qsrc = (tid & 3) ^ ((tid >> 3) & 3);
  const ushort_t* sA0 = A + ((size_t)bm * 256 + (tid >> 2)) * 1024 + qsrc * 8;
  const ushort_t* sB0 = Bmat + ((size_t)bn * 256 + (tid >> 2)) * 1024 + qsrc * 8;
  // ds_read quarter: same involution, per-lane constant (indep of m/n); BYTE offsets
  const int qrd = (lane >> 4) ^ (((lane & 15) >> 1) & 3);
  const unsigned aoffB = (unsigned)(((wr * 128 + (lane & 15)) * 32 + qrd * 8) * 2);
  const unsigned boffB = (unsigned)(((wc * 64 + (lane & 15)) * 32 + qrd * 8) * 2);
  f32x4 acc[8][4] = {};
  // prologue: stage ksubs 0,1,2 (12 loads); vmcnt(8) confirms slots A0,B0.
  stage2(sA0, lds, tid);
  stage2(sB0, lds + 32768, tid);
  stage2(sA0 + 32, lds + 8192, tid);
  stage2(sB0 + 32, lds + 32768 + 8192, tid);
  stage2(sA0 + 64, lds + 2 * 8192, tid);
  stage2(sB0 + 64, lds + 32768 + 2 * 8192, tid);
  asm volatile("s_waitcnt vmcnt(8)" ::: "memory");
  __builtin_amdgcn_s_barrier();
  // pre-loop reads for phase 0: bB[0] <- B(0), bA[0] <- A(0)lo  (8 reads)
  bf16x8 bA[2][4], bB[2][4];
  {
    const unsigned aB0 = boffB + 65536u;
    DSR(bB[0][0], aB0, "0"); DSR(bB[0][1], aB0, "1024");
    DSR(bB[0][2], aB0, "2048"); DSR(bB[0][3], aB0, "3072");
    DSR(bA[0][0], aoffB, "0"); DSR(bA[0][1], aoffB, "1024");
    DSR(bA[0][2], aoffB, "2048"); DSR(bA[0][3], aoffB, "3072");
  }
  for (int t = 0; t < 14; ++t)
    tile4<true, true, 6, 6, 6, 6, false>(t, sA0, sB0, lds, tid, aoffB, boffB, bA, bB, acc);
  tile4<true, false, 6, 6, 4, 2, false>(14, sA0, sB0, lds, tid, aoffB, boffB, bA, bB, acc);
  tile4<false, false, 0, 0, 0, 0, true>(15, sA0, sB0, lds, tid, aoffB, boffB, bA, bB, acc);
  // ---- epilogue ----
  #pragma unroll
  for (int m = 0; m < 8; m++) {
    #pragma unroll
    for (int i = 0; i < 4; i++) {
      int row = bm * 256 + wr * 128 + m * 16 + (lane >> 4) * 4 + i;
      float gw = 0.f, msum = 0.f;
      if constexpr (EPI == 3) gw = g_word[row];
      #pragma unroll
      for (int n = 0; n < 4; n++) {
        int col = bn * 256 + wc * 64 + n * 16 + (lane & 15);
        float v = acc[m][n][i];
        if constexpr (EPI == 0) {
          float z = v + bias[col];
          float gl = 0.5f * z * (1.f + erff(z * 0.70710678118f));
          hout[(size_t)row * 1024 + col] = f2bf1(gl);
        } else if constexpr (EPI == 1) {
          fout[(size_t)row * NCOL + col] = v + bias[col];
        } else if constexpr (EPI == 2) {
          float att = v + bias[col];
          float ctx = fout[(size_t)row * NCOL + col];
          float d = ctx - att;
          msum += d * d;
        } else {
          size_t off = (size_t)row * NCOL + col;
          float ctx = fout[off];
          float w = gw * sigmoidf(ctx);
          fout[off] = (1.f - w) * v + w * svec[col];
        }
      }
      if constexpr (EPI == 2) {
        #pragma unroll
        for (int o = 1; o < 16; o <<= 1) msum += __shfl_xor(msum, o, 64);
        if ((lane & 15) == 0) atomicAdd(&mse_row[row], msum);
      }
    }
  }
}

// ---------------- K7: per-row log-softmax CE ----------------
__global__ __launch_bounds__(256) void ce_kernel(const float* __restrict__ logits,
    const int* __restrict__ labels, float* __restrict__ ce_row) {
  int row = blockIdx.x, t = threadIdx.x, lane = t & 63, wave = t >> 6;
  const float* lr = logits + (size_t)row * O_;
  float v[8];
  float m = -INFINITY;
  #pragma unroll
  for (int j = 0; j < 8; j++) { v[j] = lr[t + j * 256]; m = fmaxf(m, v[j]); }
  #pragma unroll
  for (int o = 32; o; o >>= 1) m = fmaxf(m, __shfl_xor(m, o, 64));
  __shared__ float red[8];
  if (lane == 0) red[wave] = m;
  __syncthreads();
  m = fmaxf(fmaxf(red[0], red[1]), fmaxf(red[2], red[3]));
  float se = 0.f;
  #pragma unroll
  for (int j = 0; j < 8; j++) se += expf(v[j] - m);
  se = wave_sum(se);
  if (lane == 0) red[4 + wave] = se;
  __syncthreads();
  if (t == 0) {
    float bs = red[4] + red[5] + red[6] + red[7];
    int lab = labels[row];
    float nll = 0.f;
    if (lab >= 0) nll = -(lr[lab] - m - logf(bs));
    ce_row[row] = nll;
  }
}

// ---------------- K8: final scalar ----------------
__global__ __launch_bounds__(256) void finalize_kernel(const float* __restrict__ ce_row,
    const float* __restrict__ mse_row, const int* __restrict__ labels,
    float* __restrict__ out0) {
  int t = threadIdx.x, lane = t & 63, wave = t >> 6;
  float sn = 0.f, sm = 0.f, sc = 0.f;
  for (int i = t; i < B_; i += 256) {
    if (labels[i] >= 0) { sn += ce_row[i]; sm += mse_row[i]; sc += 1.f; }
  }
  sn = wave_sum(sn); sm = wave_sum(sm); sc = wave_sum(sc);
  __shared__ float r0[4], r1[4], r2[4];
  if (lane == 0) { r0[wave] = sn; r1[wave] = sm; r2[wave] = sc; }
  __syncthreads();
  if (t == 0) {
    float a = r0[0] + r0[1] + r0[2] + r0[3];
    float b = r1[0] + r1[1] + r1[2] + r1[3];
    float c = r2[0] + r2[1] + r2[2] + r2[3];
    out0[0] = (a + LAM_ * (b / (float)O_)) / fmaxf(c, 1.f);
  }
}

// ---------------- launch ----------------
extern "C" void kernel_launch(void* const* d_in, const int* in_sizes, int n_in,
                              void* d_out, int out_size, void* d_ws, size_t ws_size,
                              hipStream_t stream) {
  const float* x        = (const float*)d_in[0];
  const float* x_ctx    = (const float*)d_in[1];
  const float* cls      = (const float*)d_in[2];
  const float* none_t   = (const float*)d_in[3];
  const float* ctx_q_w  = (const float*)d_in[4];
  const float* ctx_q_b  = (const float*)d_in[5];
  const float* word_g_w = (const float*)d_in[6];
  const float* word_g_b = (const float*)d_in[7];
  const float* w1       = (const float*)d_in[8];
  const float* b1       = (const float*)d_in[9];
  const float* w2       = (const float*)d_in[10];
  const float* b2       = (const float*)d_in[11];
  const float* hist     = (const float*)d_in[12];
  const int*   hcnt     = (const int*)d_in[13];
  const int*   labels   = (const int*)d_in[14];

  float* out  = (float*)d_out;
  float* out1 = out + 1;  // logits [B x O]
  char* ws = (char*)d_ws;

  ushort_t* xbf   = (ushort_t*)(ws + WS_XBF);
  ushort_t* xcbf  = (ushort_t*)(ws + WS_XCBF);
  ushort_t* hbf   = (ushort_t*)(ws + WS_HBF);
  ushort_t* clsbf = (ushort_t*)(ws + WS_CLSBF);
  ushort_t* ctwbf = (ushort_t*)(ws + WS_CTWBF);
  ushort_t* w2bf  = (ushort_t*)(ws + WS_W2BF);
  ushort_t* w1bf  = (ushort_t*)(ws + WS_W1BF);
  float* counts   = (float*)(ws + WS_SMALL + SM_COUNTS);
  float* tsum     = (float*)(ws + WS_SMALL + SM_TSUM);
  float* mse_row  = (float*)(ws + WS_SMALL + SM_MSE);
  float* s        = (float*)(ws + WS_SMALL + SM_S);
  float* g_word   = (float*)(ws + WS_SMALL + SM_GWORD);
  float* ce_row   = (float*)(ws + WS_SMALL + SM_CEROW);

  hipMemsetAsync(ws + WS_SMALL, 0, SM_ZERO_BYTES, stream);

  f2bf_kernel<<<8192, 256, 0, stream>>>(x, xbf, B_ * D_ / 8);
  f2bf_kernel<<<8192, 256, 0, stream>>>(x_ctx, xcbf, B_ * D_ / 8);
  f2bf_kernel<<<1024, 256, 0, stream>>>(cls, clsbf, O_ * D_ / 8);
  f2bf_kernel<<<1024, 256, 0, stream>>>(ctx_q_w, ctwbf, O_ * D_ / 8);
  f2bf_kernel<<<1024, 256, 0, stream>>>(w2, w2bf, O_ * D_ / 8);
  f2bf_kernel<<<512, 256, 0, stream>>>(w1, w1bf, D_ * D_ / 8);

  rowdot_kernel<<<B_ / 4, 256, 0, stream>>>(x, cls, word_g_w, word_g_b, labels,
                                            tsum, counts, g_word);
  scls_kernel<<<O_ / 4, 256, 0, stream>>>(cls, none_t, hist, hcnt, counts, tsum, s);

  // h = gelu(x @ w1^T + b1)          [16384 x 1024] bf16
  gemm8_kernel<0, 2><<<64 * 4, 512, 0, stream>>>(xbf, w1bf, b1, nullptr, hbf,
                                                 nullptr, nullptr, nullptr);
  // ctx = x_ctx @ ctx_q_w^T + ctx_b  -> out1 (f32)
  gemm8_kernel<1, 3><<<64 * 8, 512, 0, stream>>>(xcbf, ctwbf, ctx_q_b, out1, nullptr,
                                                 nullptr, nullptr, nullptr);
  // att = h @ w2^T + b2 ; mse partials vs ctx (read out1)
  gemm8_kernel<2, 3><<<64 * 8, 512, 0, stream>>>(hbf, w2bf, b2, out1, nullptr,
                                                 nullptr, nullptr, mse_row);
  // xc = x @ cls^T ; w = gw*sigmoid(ctx) ; out1 = (1-w)*xc + w*s
  gemm8_kernel<3, 3><<<64 * 8, 512, 0, stream>>>(xbf, clsbf, nullptr, out1, nullptr,
                                                 g_word, s, nullptr);

  ce_kernel<<<B_, 256, 0, stream>>>(out1, labels, ce_row);
  finalize_kernel<<<1, 256, 0, stream>>>(ce_row, mse_row, labels, out);
}